// Round 6
// baseline (3904.545 us; speedup 1.0000x reference)
//
#include <hip/hip_runtime.h>
#include <math.h>

#define BATCH   8
#define NPTS    32768
#define FDIM    32
#define NGROUP  1024
#define GSIZE   32
#define KLANE   8       // per-lane candidate list length in KNN

// FPS: 8 blocks/batch x 512 thr x 8 pts/thr = 32768 (R13 geometry, the
// proven register-resident config: 56 VGPR).
#define NBLK    8
#define FTPB    512
#define CHUNK   (NPTS / NBLK)     // 4096 points per block
#define NFPSBLK (BATCH * NBLK)    // 64 producer blocks (first in grid)
#define KNNQPB  8                 // 8 queries (waves) per 512-thr knn block
#define NKNNBLK ((BATCH * NGROUP) / KNNQPB)   // 1024 consumer blocks
#define FASTPOLLS 8               // fast-path poll budget before fallback

// Exact float32 distance in the reference's association: ((dx^2+dy^2)+dz^2),
// contraction blocked so bits match the numpy ref (argmax stability).
__device__ __forceinline__ float dist2f(float ax, float ay, float az,
                                        float bx, float by, float bz) {
  float dx = __fsub_rn(ax, bx);
  float dy = __fsub_rn(ay, by);
  float dz = __fsub_rn(az, bz);
  return __fadd_rn(__fadd_rn(__fmul_rn(dx, dx), __fmul_rn(dy, dy)),
                   __fmul_rn(dz, dz));
}

// XCD-local L2-coherent 8B access: sc0 bypasses L0/L1 (so CUs on the SAME
// XCD see each other's stores through the shared L2) but NOT sc1 (no MALL
// round-trip -- that is the agent-scope cost these replace). Aligned 8B
// global dwordx2 ops are single-copy atomic (LLVM lowers 64-bit atomics to
// them), so the packed tag|dist|idx u64 cannot tear.
__device__ __forceinline__ void fast_store_u64(unsigned long long* p,
                                               unsigned long long v) {
  asm volatile("global_store_dwordx2 %0, %1, off sc0"
               :: "v"(p), "v"(v) : "memory");
}
__device__ __forceinline__ unsigned long long fast_load_u64(
    const unsigned long long* p) {
  unsigned long long r;
  asm volatile("global_load_dwordx2 %0, %1, off sc0\n\t"
               "s_waitcnt vmcnt(0)"
               : "=v"(r) : "v"(p) : "memory");
  return r;
}

#define X8(M) M(0) M(1) M(2) M(3) M(4) M(5) M(6) M(7)

// ---------------------------------------------------------------------------
// R20: attack the CONSENSUS SCOPE, not the protocol.
// Ledger: R13 shared-1-line agent = 2872us; R16/17 4-private agent (streamed
//   update) = 2694-2750; R19 8-private agent (reg update, clean A/B) = 3225.
//   -> protocol axis closed: agent-scope store->observe is ~1900cyc/iter
//   because AGENT atomics on 8-XCD gfx950 are coherent at the MALL, not the
//   XCD L2 (per-XCD L2s aren't cross-coherent). Every poll was a MALL RT.
// R20: all 8 producer blocks of batch b are bx%8==b -> same XCD under RR
//   dispatch -> shared L2. Candidates go through a FAST slot (sc0-only
//   inline-asm 8B store/load: L1-bypassing, L2-coherent, ~200-300cyc RT)
//   AND, always, the old agent-scope slow slot (separate lines). Pollers
//   try fast 8x then alternate fast/slow. Correctness never depends on the
//   XCD mapping (G16) -- only speed does.
// Predicted period: 450 update + ~400 reduce/barriers + ~400 consensus +
//   ~200 q-load ~= 1500-1700cyc -> dur ~1.5-1.8ms. VGPR gate: ~56.
// Failure split: ~2.9ms = sc0-L2 theory wrong; ~4.9ms = mapping broken
//   (fallback engaged, 8 wasted polls/iter).
// ---------------------------------------------------------------------------
__global__ __launch_bounds__(FTPB) void fused_kernel(
    const float* __restrict__ coord, const float* __restrict__ feat,
    const int* __restrict__ labels,
    unsigned long long* __restrict__ slots,   // [2][64] fast + [2][64] slow
    int* __restrict__ s_idx_ws,               // [8192] idx+1, pre-zeroed
    float* __restrict__ out) {
  __shared__ float redv[8];
  __shared__ int   redp[8];
  __shared__ unsigned long long bcast;

  const int bx   = blockIdx.x;
  const int tid  = threadIdx.x;
  const int lane = tid & 63;
  const int wid  = tid >> 6;          // 0..7

  if (bx < NFPSBLK) {
    // ===================== FPS (producer) =====================
    const int b    = bx & 7;          // batch (XCD-local under %8 mapping)
    const int bk   = bx >> 3;         // block within batch: 0..7
    const float* __restrict__ c = coord + (size_t)b * NPTS * 3;
    const float3* __restrict__ c3 = (const float3*)c;
    const int pbase = bk * CHUNK + tid;

#define DECL8(i) float x##i, y##i, z##i, d##i;
    X8(DECL8)
#undef DECL8

    // Init: distance to batch point 0; local argmax (ascending index +
    // strict > == np.argmax lowest-index tie-break).
    float qx = c[0], qy = c[1], qz = c[2];
    float bestv = -1.0f; int bestp = 0;
#define LOAD8(i) { int p = pbase + (i) * FTPB; float3 v = c3[p];            \
    x##i = v.x; y##i = v.y; z##i = v.z;                                      \
    float t2 = dist2f(v.x, v.y, v.z, qx, qy, qz); d##i = t2;                 \
    if (t2 > bestv) { bestv = t2; bestp = p; } }
    X8(LOAD8)
#undef LOAD8

    if (bk == 0 && tid == 0)
      __hip_atomic_store(&s_idx_ws[b * NGROUP + 0], 1, __ATOMIC_RELAXED,
                         __HIP_MEMORY_SCOPE_AGENT);   // idx 0, +1 encoding

    for (int t = 1; t < NGROUP; ++t) {
      // Wave-level argmax (max value, tie -> min index).
      float v = bestv; int p = bestp;
      #pragma unroll
      for (int m = 1; m < 64; m <<= 1) {
        float ov = __shfl_xor(v, m, 64);
        int   op = __shfl_xor(p, m, 64);
        if (ov > v || (ov == v && op < p)) { v = ov; p = op; }
      }
      if (lane == 0) { redv[wid] = v; redp[wid] = p; }
      __syncthreads();   // B1

      if (wid == 0) {
        float gv = redv[lane & 7]; int gp = redp[lane & 7];
        #pragma unroll
        for (int m = 1; m < 8; m <<= 1) {
          float ov = __shfl_xor(gv, m, 64);
          int   op = __shfl_xor(gp, m, 64);
          if (ov > gv || (ov == gv && op < gp)) { gv = ov; gp = op; }
        }
        // fast slots: [2][64]; slow slots: +128 offset, [2][64].
        unsigned long long* fbase =
            slots + (size_t)(t & 1) * (BATCH * NBLK);
        unsigned long long* sbase =
            slots + 2 * (BATCH * NBLK) + (size_t)(t & 1) * (BATCH * NBLK);
        if (lane == 0) {
          unsigned long long pk = ((unsigned long long)t << 47)
                                | ((unsigned long long)__float_as_uint(gv) << 15)
                                | (unsigned long long)(0x7FFF - gp);
          fast_store_u64(fbase + (b << 3) + bk, pk);        // XCD-L2 path
          __hip_atomic_store(sbase + (b << 3) + bk, pk,     // agent fallback
                             __ATOMIC_RELEASE, __HIP_MEMORY_SCOPE_AGENT);
        }
        unsigned long long pk2 = 0;
        if (lane < 8) {
          const unsigned long long* fs = fbase + (b << 3) + lane;
          const unsigned long long* ss = sbase + (b << 3) + lane;
          #pragma unroll 1
          for (int k = 0; k < FASTPOLLS; ++k) {
            pk2 = fast_load_u64(fs);
            if ((int)(pk2 >> 47) == t) break;
          }
          while ((int)(pk2 >> 47) != t) {
            pk2 = fast_load_u64(fs);
            if ((int)(pk2 >> 47) == t) break;
            pk2 = __hip_atomic_load(ss, __ATOMIC_ACQUIRE,
                                    __HIP_MEMORY_SCOPE_AGENT);
          }
        }
        #pragma unroll
        for (int m = 1; m < 8; m <<= 1) {
          unsigned long long o = __shfl_xor(pk2, m, 64);
          if (o > pk2) pk2 = o;
        }
        if (lane == 0) bcast = pk2;
      }
      __syncthreads();   // B2

      const unsigned long long wpk = bcast;
      const int gp = 0x7FFF - (int)(wpk & 0x7FFF);
      if (bk == 0 && tid == 0)
        __hip_atomic_store(&s_idx_ws[b * NGROUP + t], gp + 1,
                           __ATOMIC_RELAXED, __HIP_MEMORY_SCOPE_AGENT);
      if (t == NGROUP - 1) break;

      float3 q = c3[gp];
      qx = q.x; qy = q.y; qz = q.z;
      bestv = -1.0f; bestp = 0;
#define UPD8(i) { float t2 = dist2f(x##i, y##i, z##i, qx, qy, qz);           \
    float nd = fminf(d##i, t2); d##i = nd;                                   \
    if (nd > bestv) { bestv = nd; bestp = pbase + (i) * FTPB; } }
      X8(UPD8)
#undef UPD8
    }
    return;
  }

  // ===================== KNN (consumer) =====================
  const int qid = (bx - NFPSBLK) * KNNQPB + wid;   // 0..8191
  const int b   = qid >> 10;
  const float* __restrict__ c = coord + (size_t)b * NPTS * 3;

  // Conservative backoff (well under estimated publish time at ~1.6us/iter),
  // then slow spin. s_sleep counts CORE CLOCKS (R12 lesson): undersleep safe.
  const int tq = qid & (NGROUP - 1);
  int enc = __hip_atomic_load(&s_idx_ws[qid], __ATOMIC_RELAXED,
                              __HIP_MEMORY_SCOPE_AGENT);
  for (int i = tq >> 3; i > 0 && enc == 0; --i) {
    __builtin_amdgcn_s_sleep(127);
    enc = __hip_atomic_load(&s_idx_ws[qid], __ATOMIC_RELAXED,
                            __HIP_MEMORY_SCOPE_AGENT);
  }
  while (enc == 0) {
    __builtin_amdgcn_s_sleep(64);
    enc = __hip_atomic_load(&s_idx_ws[qid], __ATOMIC_RELAXED,
                            __HIP_MEMORY_SCOPE_AGENT);
  }
  const int sp = __builtin_amdgcn_readfirstlane(enc - 1);
  const int gq = b * NPTS + sp;
  const float qx = coord[(size_t)gq * 3 + 0];
  const float qy = coord[(size_t)gq * 3 + 1];
  const float qz = coord[(size_t)gq * 3 + 2];

  // Per-lane ascending top-8 (value, index), static indexing only.
  float lv[KLANE]; int li[KLANE];
  #pragma unroll
  for (int j = 0; j < KLANE; ++j) { lv[j] = 1e30f; li[j] = 0x7fffffff; }

  // Branchless sorted insert; strict < keeps equal-distance earlier (lower)
  // indices first, matching lax.top_k tie order.
#define INSERT(D2, P) \
  if ((D2) < lv[KLANE - 1]) { \
    _Pragma("unroll") \
    for (int j = KLANE - 1; j >= 1; --j) { \
      bool up = (D2) < lv[j - 1]; \
      float nv = up ? lv[j - 1] : (((D2) < lv[j]) ? (D2) : lv[j]); \
      int   ni = up ? li[j - 1] : (((D2) < lv[j]) ? (P)  : li[j]); \
      lv[j] = nv; li[j] = ni; \
    } \
    if ((D2) < lv[0]) { lv[0] = (D2); li[0] = (P); } \
  }

  for (int s = 0; s < NPTS / 256; ++s) {   // 128 iterations, 4 pts/lane
    int p = (s << 8) | (lane << 2);
    const float4* c4 = (const float4*)(c + (size_t)p * 3);
    float4 f0 = c4[0], f1 = c4[1], f2 = c4[2];
    float dA = dist2f(f0.x, f0.y, f0.z, qx, qy, qz);
    float dB = dist2f(f0.w, f1.x, f1.y, qx, qy, qz);
    float dC = dist2f(f1.z, f1.w, f2.x, qx, qy, qz);
    float dD = dist2f(f2.y, f2.z, f2.w, qx, qy, qz);
    INSERT(dA, p);
    INSERT(dB, p + 1);
    INSERT(dC, p + 2);
    INSERT(dD, p + 3);
  }
#undef INSERT

  // Extract the 32 globally smallest (ascending, tie -> lower index).
  // Round 0 is the query itself (d2 == 0), excluded from the angle mean
  // like angles[:, :, 1:].
  int nbp = 0;
  for (int r = 0; r < GSIZE; ++r) {
    float mv = lv[0]; int mp = li[0];
    #pragma unroll
    for (int m = 1; m < 64; m <<= 1) {
      float ov = __shfl_xor(mv, m, 64);
      int   op = __shfl_xor(mp, m, 64);
      if (ov < mv || (ov == mv && op < mp)) { mv = ov; mp = op; }
    }
    if (lane == r) nbp = mp;
    if (lv[0] == mv && li[0] == mp) {  // unique winner pops its head
      #pragma unroll
      for (int j = 0; j < KLANE - 1; ++j) { lv[j] = lv[j + 1]; li[j] = li[j + 1]; }
      lv[KLANE - 1] = 1e30f; li[KLANE - 1] = 0x7fffffff;
    }
  }

  // Angle for lanes 1..31: theta = 2*atan2(||a*|b| - |a|*b||, ||a*|b| + |a|*b||)
  const float* aRow = feat + (size_t)gq * FDIM;
  float my_a = (lane < FDIM) ? aRow[lane] : 0.0f;

  float ang = 0.0f;
  if (lane >= 1 && lane < GSIZE) {
    const float4* a4 = (const float4*)aRow;
    const float4* b4 = (const float4*)(feat + ((size_t)b * NPTS + nbp) * FDIM);
    float4 av[FDIM / 4], bv[FDIM / 4];
    float aa = 0.0f, bb = 0.0f;
    #pragma unroll
    for (int k = 0; k < FDIM / 4; ++k) {
      av[k] = a4[k]; bv[k] = b4[k];
      aa += av[k].x * av[k].x + av[k].y * av[k].y + av[k].z * av[k].z + av[k].w * av[k].w;
      bb += bv[k].x * bv[k].x + bv[k].y * bv[k].y + bv[k].z * bv[k].z + bv[k].w * bv[k].w;
    }
    float an = sqrtf(aa), bn = sqrtf(bb);
    float num2 = 0.0f, den2 = 0.0f;
    #pragma unroll
    for (int k = 0; k < FDIM / 4; ++k) {
      float n0 = av[k].x * bn - an * bv[k].x, dd0 = av[k].x * bn + an * bv[k].x;
      float n1 = av[k].y * bn - an * bv[k].y, dd1 = av[k].y * bn + an * bv[k].y;
      float n2 = av[k].z * bn - an * bv[k].z, dd2 = av[k].z * bn + an * bv[k].z;
      float n3 = av[k].w * bn - an * bv[k].w, dd3 = av[k].w * bn + an * bv[k].w;
      num2 += n0 * n0 + n1 * n1 + n2 * n2 + n3 * n3;
      den2 += dd0 * dd0 + dd1 * dd1 + dd2 * dd2 + dd3 * dd3;
    }
    ang = 2.0f * atan2f(sqrtf(num2), sqrtf(den2));
  }

  // Wave sum of the 31 angles -> p_curv everywhere.
  float tot = ang;
  #pragma unroll
  for (int m = 1; m < 64; m <<= 1) tot += __shfl_xor(tot, m, 64);
  float p_curv = tot / 31.0f;

  // Outputs (flat concatenation, all as float32).
  float* out_xyz  = out;                              // 8192*3
  float* out_feat = out + (size_t)BATCH * NGROUP * 3; // 8192*33
  float* out_sw   = out_feat + (size_t)BATCH * NGROUP * (FDIM + 1);
  float* out_lab  = out_sw  + (size_t)BATCH * NGROUP;
  float* out_sif  = out_lab + (size_t)BATCH * NGROUP;

  if (lane < FDIM)  out_feat[(size_t)qid * (FDIM + 1) + lane] = my_a;
  if (lane == FDIM) out_feat[(size_t)qid * (FDIM + 1) + FDIM] = p_curv;
  if (lane == 0) {
    out_xyz[(size_t)qid * 3 + 0] = qx;
    out_xyz[(size_t)qid * 3 + 1] = qy;
    out_xyz[(size_t)qid * 3 + 2] = qz;
    out_sw[qid]  = (p_curv > 0.087266f) ? 1.0f : 0.0f;
    out_lab[qid] = (float)labels[gq];
    out_sif[qid] = (float)gq;   // s_idx + b*N
  }
}

extern "C" void kernel_launch(void* const* d_in, const int* in_sizes, int n_in,
                              void* d_out, int out_size, void* d_ws, size_t ws_size,
                              hipStream_t stream) {
  const float* coord  = (const float*)d_in[0];
  const float* feat   = (const float*)d_in[1];
  const int*   labels = (const int*)d_in[2];

  // ws layout: [2][64] u64 FAST slots (XCD-L2 path) + [2][64] u64 SLOW
  // slots (agent fallback), then [8192] int s_idx (+1 encoded). All zeroed.
  unsigned long long* slots = (unsigned long long*)d_ws;
  int* s_idx_ws = (int*)((char*)d_ws +
                         4 * BATCH * NBLK * sizeof(unsigned long long));
  const size_t zbytes = 4 * BATCH * NBLK * sizeof(unsigned long long)
                      + (size_t)BATCH * NGROUP * sizeof(int);

  hipMemsetAsync(d_ws, 0, zbytes, stream);
  fused_kernel<<<NFPSBLK + NKNNBLK, FTPB, 0, stream>>>(
      coord, feat, labels, slots, s_idx_ws, (float*)d_out);
}

// Round 7
// 2453.383 us; speedup vs baseline: 1.5915x; 1.5915x over previous
//
#include <hip/hip_runtime.h>
#include <math.h>

#define BATCH   8
#define NPTS    32768
#define FDIM    32
#define NGROUP  1024
#define GSIZE   32
#define KLANE   8       // per-lane candidate list length in KNN

// FPS: 8 blocks/batch x 512 thr x 8 pts/thr = 32768 (R13 geometry, proven
// register-resident: 56 VGPR).
#define NBLK    8
#define FTPB    512
#define CHUNK   (NPTS / NBLK)     // 4096 points per block
#define NFPSBLK (BATCH * NBLK)    // 64 producer blocks (first in grid)
#define KNNQPB  8                 // 8 queries (waves) per 512-thr knn block
#define NKNNBLK ((BATCH * NGROUP) / KNNQPB)   // 1024 consumer blocks

// Exact float32 distance in the reference's association: ((dx^2+dy^2)+dz^2),
// contraction blocked so bits match the numpy ref (argmax stability).
__device__ __forceinline__ float dist2f(float ax, float ay, float az,
                                        float bx, float by, float bz) {
  float dx = __fsub_rn(ax, bx);
  float dy = __fsub_rn(ay, by);
  float dz = __fsub_rn(az, bz);
  return __fadd_rn(__fadd_rn(__fmul_rn(dx, dx), __fmul_rn(dy, dy)),
                   __fmul_rn(dz, dz));
}

#define X8(M) M(0) M(1) M(2) M(3) M(4) M(5) M(6) M(7)

// ---------------------------------------------------------------------------
// R21 = R13 VERBATIM except memory ORDER: all slot atomics RELAXED.
// Ledger (all A/B'd on this problem):
//   R13 shared-line acq/rel           = 2872us  <- base (best measured)
//   R16/17 private-lines acq/rel      = 2694-2750 (confounded: streamed upd)
//   R19 8-private-lines acq/rel       = 3225  (clean; MORE lines = WORSE)
//   R20 sc0-fast + agent-slow dual    = 3790  (2x stores+polls = worse yet)
// -> cost scales with WORK PER POLL ROUND (lines fetched, fences), not with
//    writer count or propagation parallelism. Every variant paid an
//    agent-scope ACQUIRE per poll iteration: on gfx94x+ that's a cache-inv
//    + waitcnt EVERY round of the divergent 8-lane poll loop -- the ~0.8-1us
//    poll cadence that dominates the 2.8us period.
// The ordering is unnecessary: the only cross-block data is ONE 8-byte
// packed word (tag|dist|idx, single-copy atomic). No other producer-written
// memory is consumed through it (coords are read-only; bcast is ordered by
// __syncthreads; consumer s_idx word is likewise self-contained). RELAXED
// keeps scope (visibility) and drops all per-poll fence cost.
// Predicted: VGPR 56 (gate); dur 2872 -> ~1900-2300us if acquire-overhead
// theory holds; ~2850 = null -> floor is true propagation+straggler, go
// single-block-per-batch (consensus-free) or declare floor.
// ---------------------------------------------------------------------------
__global__ __launch_bounds__(FTPB) void fused_kernel(
    const float* __restrict__ coord, const float* __restrict__ feat,
    const int* __restrict__ labels,
    unsigned long long* __restrict__ slots,   // [2][64] u64, pre-zeroed
    int* __restrict__ s_idx_ws,               // [8192] idx+1, pre-zeroed
    float* __restrict__ out) {
  __shared__ float redv[8];
  __shared__ int   redp[8];
  __shared__ unsigned long long bcast;

  const int bx   = blockIdx.x;
  const int tid  = threadIdx.x;
  const int lane = tid & 63;
  const int wid  = tid >> 6;          // 0..7

  if (bx < NFPSBLK) {
    // ===================== FPS (producer) =====================
    const int b    = bx & 7;          // batch (XCD-local under %8 mapping)
    const int bk   = bx >> 3;         // block within batch
    const float* __restrict__ c = coord + (size_t)b * NPTS * 3;
    const float3* __restrict__ c3 = (const float3*)c;
    const int pbase = bk * CHUNK + tid;

#define DECL8(i) float x##i, y##i, z##i, d##i;
    X8(DECL8)
#undef DECL8

    // Init: distance to batch point 0; local argmax (ascending index +
    // strict > == np.argmax lowest-index tie-break).
    float qx = c[0], qy = c[1], qz = c[2];
    float bestv = -1.0f; int bestp = 0;
#define LOAD8(i) { int p = pbase + (i) * FTPB; float3 v = c3[p];            \
    x##i = v.x; y##i = v.y; z##i = v.z;                                      \
    float t2 = dist2f(v.x, v.y, v.z, qx, qy, qz); d##i = t2;                 \
    if (t2 > bestv) { bestv = t2; bestp = p; } }
    X8(LOAD8)
#undef LOAD8

    if (bk == 0 && tid == 0)
      __hip_atomic_store(&s_idx_ws[b * NGROUP + 0], 1, __ATOMIC_RELAXED,
                         __HIP_MEMORY_SCOPE_AGENT);   // idx 0, +1 encoding

    for (int t = 1; t < NGROUP; ++t) {
      // Wave-level argmax (max value, tie -> min index).
      float v = bestv; int p = bestp;
      #pragma unroll
      for (int m = 1; m < 64; m <<= 1) {
        float ov = __shfl_xor(v, m, 64);
        int   op = __shfl_xor(p, m, 64);
        if (ov > v || (ov == v && op < p)) { v = ov; p = op; }
      }
      if (lane == 0) { redv[wid] = v; redp[wid] = p; }
      __syncthreads();   // B1

      if (wid == 0) {
        float gv = redv[lane & 7]; int gp = redp[lane & 7];
        #pragma unroll
        for (int m = 1; m < 8; m <<= 1) {
          float ov = __shfl_xor(gv, m, 64);
          int   op = __shfl_xor(gp, m, 64);
          if (ov > gv || (ov == gv && op < gp)) { gv = ov; gp = op; }
        }
        unsigned long long* base = slots + (size_t)(t & 1) * (BATCH * NBLK);
        if (lane == 0) {
          unsigned long long pk = ((unsigned long long)t << 47)
                                | ((unsigned long long)__float_as_uint(gv) << 15)
                                | (unsigned long long)(0x7FFF - gp);
          __hip_atomic_store(base + (b << 3) + bk, pk, __ATOMIC_RELAXED,
                             __HIP_MEMORY_SCOPE_AGENT);
        }
        unsigned long long pk2 = 0;
        if (lane < 8) {
          const unsigned long long* sl = base + (b << 3) + lane;
          do {
            pk2 = __hip_atomic_load(sl, __ATOMIC_RELAXED,
                                    __HIP_MEMORY_SCOPE_AGENT);
          } while ((int)(pk2 >> 47) != t);
        }
        #pragma unroll
        for (int m = 1; m < 8; m <<= 1) {
          unsigned long long o = __shfl_xor(pk2, m, 64);
          if (o > pk2) pk2 = o;
        }
        if (lane == 0) bcast = pk2;
      }
      __syncthreads();   // B2

      const unsigned long long wpk = bcast;
      const int gp = 0x7FFF - (int)(wpk & 0x7FFF);
      if (bk == 0 && tid == 0)
        __hip_atomic_store(&s_idx_ws[b * NGROUP + t], gp + 1,
                           __ATOMIC_RELAXED, __HIP_MEMORY_SCOPE_AGENT);
      if (t == NGROUP - 1) break;

      float3 q = c3[gp];
      qx = q.x; qy = q.y; qz = q.z;
      bestv = -1.0f; bestp = 0;
#define UPD8(i) { float t2 = dist2f(x##i, y##i, z##i, qx, qy, qz);           \
    float nd = fminf(d##i, t2); d##i = nd;                                   \
    if (nd > bestv) { bestv = nd; bestp = pbase + (i) * FTPB; } }
      X8(UPD8)
#undef UPD8
    }
    return;
  }

  // ===================== KNN (consumer) =====================
  const int qid = (bx - NFPSBLK) * KNNQPB + wid;   // 0..8191
  const int b   = qid >> 10;
  const float* __restrict__ c = coord + (size_t)b * NPTS * 3;

  // Conservative backoff (~1/3 of estimated publish time in s_sleep(127)
  // chunks -- s_sleep counts CORE CLOCKS, R12 lesson), then slow spin.
  const int tq = qid & (NGROUP - 1);
  int enc = __hip_atomic_load(&s_idx_ws[qid], __ATOMIC_RELAXED,
                              __HIP_MEMORY_SCOPE_AGENT);
  for (int i = tq >> 2; i > 0 && enc == 0; --i) {
    __builtin_amdgcn_s_sleep(127);
    enc = __hip_atomic_load(&s_idx_ws[qid], __ATOMIC_RELAXED,
                            __HIP_MEMORY_SCOPE_AGENT);
  }
  while (enc == 0) {
    __builtin_amdgcn_s_sleep(64);
    enc = __hip_atomic_load(&s_idx_ws[qid], __ATOMIC_RELAXED,
                            __HIP_MEMORY_SCOPE_AGENT);
  }
  const int sp = __builtin_amdgcn_readfirstlane(enc - 1);
  const int gq = b * NPTS + sp;
  const float qx = coord[(size_t)gq * 3 + 0];
  const float qy = coord[(size_t)gq * 3 + 1];
  const float qz = coord[(size_t)gq * 3 + 2];

  // Per-lane ascending top-8 (value, index), static indexing only.
  float lv[KLANE]; int li[KLANE];
  #pragma unroll
  for (int j = 0; j < KLANE; ++j) { lv[j] = 1e30f; li[j] = 0x7fffffff; }

  // Branchless sorted insert; strict < keeps equal-distance earlier (lower)
  // indices first, matching lax.top_k tie order.
#define INSERT(D2, P) \
  if ((D2) < lv[KLANE - 1]) { \
    _Pragma("unroll") \
    for (int j = KLANE - 1; j >= 1; --j) { \
      bool up = (D2) < lv[j - 1]; \
      float nv = up ? lv[j - 1] : (((D2) < lv[j]) ? (D2) : lv[j]); \
      int   ni = up ? li[j - 1] : (((D2) < lv[j]) ? (P)  : li[j]); \
      lv[j] = nv; li[j] = ni; \
    } \
    if ((D2) < lv[0]) { lv[0] = (D2); li[0] = (P); } \
  }

  for (int s = 0; s < NPTS / 256; ++s) {   // 128 iterations, 4 pts/lane
    int p = (s << 8) | (lane << 2);
    const float4* c4 = (const float4*)(c + (size_t)p * 3);
    float4 f0 = c4[0], f1 = c4[1], f2 = c4[2];
    float dA = dist2f(f0.x, f0.y, f0.z, qx, qy, qz);
    float dB = dist2f(f0.w, f1.x, f1.y, qx, qy, qz);
    float dC = dist2f(f1.z, f1.w, f2.x, qx, qy, qz);
    float dD = dist2f(f2.y, f2.z, f2.w, qx, qy, qz);
    INSERT(dA, p);
    INSERT(dB, p + 1);
    INSERT(dC, p + 2);
    INSERT(dD, p + 3);
  }
#undef INSERT

  // Extract the 32 globally smallest (ascending, tie -> lower index).
  // Round 0 is the query itself (d2 == 0), excluded from the angle mean
  // like angles[:, :, 1:].
  int nbp = 0;
  for (int r = 0; r < GSIZE; ++r) {
    float mv = lv[0]; int mp = li[0];
    #pragma unroll
    for (int m = 1; m < 64; m <<= 1) {
      float ov = __shfl_xor(mv, m, 64);
      int   op = __shfl_xor(mp, m, 64);
      if (ov < mv || (ov == mv && op < mp)) { mv = ov; mp = op; }
    }
    if (lane == r) nbp = mp;
    if (lv[0] == mv && li[0] == mp) {  // unique winner pops its head
      #pragma unroll
      for (int j = 0; j < KLANE - 1; ++j) { lv[j] = lv[j + 1]; li[j] = li[j + 1]; }
      lv[KLANE - 1] = 1e30f; li[KLANE - 1] = 0x7fffffff;
    }
  }

  // Angle for lanes 1..31: theta = 2*atan2(||a*|b| - |a|*b||, ||a*|b| + |a|*b||)
  const float* aRow = feat + (size_t)gq * FDIM;
  float my_a = (lane < FDIM) ? aRow[lane] : 0.0f;

  float ang = 0.0f;
  if (lane >= 1 && lane < GSIZE) {
    const float4* a4 = (const float4*)aRow;
    const float4* b4 = (const float4*)(feat + ((size_t)b * NPTS + nbp) * FDIM);
    float4 av[FDIM / 4], bv[FDIM / 4];
    float aa = 0.0f, bb = 0.0f;
    #pragma unroll
    for (int k = 0; k < FDIM / 4; ++k) {
      av[k] = a4[k]; bv[k] = b4[k];
      aa += av[k].x * av[k].x + av[k].y * av[k].y + av[k].z * av[k].z + av[k].w * av[k].w;
      bb += bv[k].x * bv[k].x + bv[k].y * bv[k].y + bv[k].z * bv[k].z + bv[k].w * bv[k].w;
    }
    float an = sqrtf(aa), bn = sqrtf(bb);
    float num2 = 0.0f, den2 = 0.0f;
    #pragma unroll
    for (int k = 0; k < FDIM / 4; ++k) {
      float n0 = av[k].x * bn - an * bv[k].x, dd0 = av[k].x * bn + an * bv[k].x;
      float n1 = av[k].y * bn - an * bv[k].y, dd1 = av[k].y * bn + an * bv[k].y;
      float n2 = av[k].z * bn - an * bv[k].z, dd2 = av[k].z * bn + an * bv[k].z;
      float n3 = av[k].w * bn - an * bv[k].w, dd3 = av[k].w * bn + an * bv[k].w;
      num2 += n0 * n0 + n1 * n1 + n2 * n2 + n3 * n3;
      den2 += dd0 * dd0 + dd1 * dd1 + dd2 * dd2 + dd3 * dd3;
    }
    ang = 2.0f * atan2f(sqrtf(num2), sqrtf(den2));
  }

  // Wave sum of the 31 angles -> p_curv everywhere.
  float tot = ang;
  #pragma unroll
  for (int m = 1; m < 64; m <<= 1) tot += __shfl_xor(tot, m, 64);
  float p_curv = tot / 31.0f;

  // Outputs (flat concatenation, all as float32).
  float* out_xyz  = out;                              // 8192*3
  float* out_feat = out + (size_t)BATCH * NGROUP * 3; // 8192*33
  float* out_sw   = out_feat + (size_t)BATCH * NGROUP * (FDIM + 1);
  float* out_lab  = out_sw  + (size_t)BATCH * NGROUP;
  float* out_sif  = out_lab + (size_t)BATCH * NGROUP;

  if (lane < FDIM)  out_feat[(size_t)qid * (FDIM + 1) + lane] = my_a;
  if (lane == FDIM) out_feat[(size_t)qid * (FDIM + 1) + FDIM] = p_curv;
  if (lane == 0) {
    out_xyz[(size_t)qid * 3 + 0] = qx;
    out_xyz[(size_t)qid * 3 + 1] = qy;
    out_xyz[(size_t)qid * 3 + 2] = qz;
    out_sw[qid]  = (p_curv > 0.087266f) ? 1.0f : 0.0f;
    out_lab[qid] = (float)labels[gq];
    out_sif[qid] = (float)gq;   // s_idx + b*N
  }
}

extern "C" void kernel_launch(void* const* d_in, const int* in_sizes, int n_in,
                              void* d_out, int out_size, void* d_ws, size_t ws_size,
                              hipStream_t stream) {
  const float* coord  = (const float*)d_in[0];
  const float* feat   = (const float*)d_in[1];
  const int*   labels = (const int*)d_in[2];

  // ws layout: [2][64] u64 ping-pong slots, then [8192] int s_idx (+1
  // encoded, 0 = unpublished). Both must start zeroed.
  unsigned long long* slots = (unsigned long long*)d_ws;
  int* s_idx_ws = (int*)((char*)d_ws +
                         2 * BATCH * NBLK * sizeof(unsigned long long));
  const size_t zbytes = 2 * BATCH * NBLK * sizeof(unsigned long long)
                      + (size_t)BATCH * NGROUP * sizeof(int);

  hipMemsetAsync(d_ws, 0, zbytes, stream);
  fused_kernel<<<NFPSBLK + NKNNBLK, FTPB, 0, stream>>>(
      coord, feat, labels, slots, s_idx_ws, (float*)d_out);
}